// Round 1
// baseline (6079.037 us; speedup 1.0000x reference)
//
#include <hip/hip_runtime.h>

// ---------------------------------------------------------------------------
// HypComEnc: 2-layer hyperbolic GCN encoder + segment mean pool (c = 1)
// N=100000 nodes, D0=256, D=128, E=1600000 edges, S=1600 segments
// ---------------------------------------------------------------------------

#define MAXN 0.996f          // 1 - PROJ_EPS
#define CLIPV 0.9999999f     // 1 - 1e-7 (artanh clip)
#define MINNORM 1e-15f

__device__ __forceinline__ float wave_sum(float v) {
#pragma unroll
  for (int o = 32; o > 0; o >>= 1) v += __shfl_xor(v, o);
  return v;
}

// --- per-row scale of proj(expmap0(x)) for the 256-wide input ---------------
// h0 = f * x ; xn = ||h0||
__global__ void row_scale_kernel(const float* __restrict__ X,
                                 float* __restrict__ fbuf,
                                 float* __restrict__ xnbuf, int M) {
  int row = blockIdx.x * 4 + (threadIdx.x >> 6);
  int lane = threadIdx.x & 63;
  if (row >= M) return;
  float4 v = *reinterpret_cast<const float4*>(&X[(size_t)row * 256 + lane * 4]);
  float ssq = wave_sum(v.x * v.x + v.y * v.y + v.z * v.z + v.w * v.w);
  float un = fmaxf(sqrtf(ssq), MINNORM);
  float t = tanhf(un);
  float f, xn;
  if (t > MAXN) { f = MAXN / un; xn = MAXN; }
  else          { f = t / un;    xn = t; }
  if (lane == 0) { fbuf[row] = f; xnbuf[row] = xn; }
}

// --- hb = proj(expmap0(b)), y2 = ||hb||^2 ; 1 block x 64 threads, dim 128 ---
__global__ void bias_kernel(const float* __restrict__ b,
                            float* __restrict__ hb, float* __restrict__ y2out) {
  int lane = threadIdx.x;
  float b0 = b[lane], b1 = b[lane + 64];
  float ssq = wave_sum(b0 * b0 + b1 * b1);
  float un = fmaxf(sqrtf(ssq), MINNORM);
  float t = tanhf(un);
  float s = t / un;
  float n = t;
  if (n > MAXN) { s *= MAXN / n; n = MAXN; }
  hb[lane] = s * b0;
  hb[lane + 64] = s * b1;
  if (lane == 0) y2out[0] = n * n;
}

// --- GEMM: Out[m][n] = sum_k X[m][k] * W[n][k], N fixed = 128 ---------------
// 128x128 tile, BK=16, 256 threads, 8x8 register tile / thread
__global__ __launch_bounds__(256) void gemm_xwT(const float* __restrict__ X,
                                                const float* __restrict__ W,
                                                float* __restrict__ Out,
                                                int M, int K) {
  __shared__ float Xs[16][132];
  __shared__ float Ws[16][132];
  int m0 = blockIdx.x * 128;
  int tid = threadIdx.x;
  int tx = tid & 15;   // n = tx*8 .. +7
  int ty = tid >> 4;   // m = ty*8 .. +7
  float acc[8][8];
#pragma unroll
  for (int i = 0; i < 8; i++)
#pragma unroll
    for (int j = 0; j < 8; j++) acc[i][j] = 0.f;

  for (int k0 = 0; k0 < K; k0 += 16) {
#pragma unroll
    for (int half = 0; half < 2; half++) {
      int r = (tid >> 2) + half * 64;
      int kk = (tid & 3) * 4;
      int gm = m0 + r;
      float4 v = make_float4(0.f, 0.f, 0.f, 0.f);
      if (gm < M) v = *reinterpret_cast<const float4*>(&X[(size_t)gm * K + k0 + kk]);
      Xs[kk + 0][r] = v.x; Xs[kk + 1][r] = v.y;
      Xs[kk + 2][r] = v.z; Xs[kk + 3][r] = v.w;
      int n = (tid >> 2) + half * 64;
      float4 w = *reinterpret_cast<const float4*>(&W[(size_t)n * K + k0 + kk]);
      Ws[kk + 0][n] = w.x; Ws[kk + 1][n] = w.y;
      Ws[kk + 2][n] = w.z; Ws[kk + 3][n] = w.w;
    }
    __syncthreads();
#pragma unroll
    for (int k = 0; k < 16; k++) {
      float4 a0 = *reinterpret_cast<const float4*>(&Xs[k][ty * 8]);
      float4 a1 = *reinterpret_cast<const float4*>(&Xs[k][ty * 8 + 4]);
      float4 b0 = *reinterpret_cast<const float4*>(&Ws[k][tx * 8]);
      float4 b1 = *reinterpret_cast<const float4*>(&Ws[k][tx * 8 + 4]);
      float a[8] = {a0.x, a0.y, a0.z, a0.w, a1.x, a1.y, a1.z, a1.w};
      float b[8] = {b0.x, b0.y, b0.z, b0.w, b1.x, b1.y, b1.z, b1.w};
#pragma unroll
      for (int i = 0; i < 8; i++)
#pragma unroll
        for (int j = 0; j < 8; j++) acc[i][j] = fmaf(a[i], b[j], acc[i][j]);
    }
    __syncthreads();
  }
#pragma unroll
  for (int i = 0; i < 8; i++) {
    int gm = m0 + ty * 8 + i;
    if (gm >= M) continue;
    float4 v0 = make_float4(acc[i][0], acc[i][1], acc[i][2], acc[i][3]);
    float4 v1 = make_float4(acc[i][4], acc[i][5], acc[i][6], acc[i][7]);
    *reinterpret_cast<float4*>(&Out[(size_t)gm * 128 + tx * 8]) = v0;
    *reinterpret_cast<float4*>(&Out[(size_t)gm * 128 + tx * 8 + 4]) = v1;
  }
}

// --- post-GEMM: mobius_matvec tail + proj + mobius_add(bias) + proj + logmap0
// If fbuf != null: mx = f*G, xn precomputed (layer 1). Else: f=1, xn=||Xh row||.
__global__ void post_gemm_kernel(float* __restrict__ G,
                                 const float* __restrict__ fbuf,
                                 const float* __restrict__ xnbuf,
                                 const float* __restrict__ Xh,
                                 const float* __restrict__ hb,
                                 const float* __restrict__ y2buf, int M) {
  int row = blockIdx.x * 4 + (threadIdx.x >> 6);
  int lane = threadIdx.x & 63;
  if (row >= M) return;
  float f, xn;
  if (fbuf) {
    f = fbuf[row]; xn = xnbuf[row];
  } else {
    f = 1.0f;
    float2 xr = *reinterpret_cast<const float2*>(&Xh[(size_t)row * 128 + lane * 2]);
    xn = fmaxf(sqrtf(wave_sum(xr.x * xr.x + xr.y * xr.y)), MINNORM);
  }
  float2 g = *reinterpret_cast<const float2*>(&G[(size_t)row * 128 + lane * 2]);
  float mx0 = f * g.x, mx1 = f * g.y;
  float mxn = fmaxf(sqrtf(wave_sum(mx0 * mx0 + mx1 * mx1)), MINNORM);
  float art = atanhf(fminf(xn, CLIPV));
  float t = tanhf(mxn / xn * art);
  float s = t / mxn;          // res = s*mx, ||res|| = t
  float rn = t;
  if (rn > MAXN) { s *= MAXN / rn; rn = MAXN; }
  float v0 = s * mx0, v1 = s * mx1;
  float x2 = rn * rn;
  float hb0 = hb[lane * 2], hb1 = hb[lane * 2 + 1];
  float y2 = y2buf[0];
  float xy = wave_sum(v0 * hb0 + v1 * hb1);
  float ca = 1.0f + 2.0f * xy + y2;
  float cb = 1.0f - x2;
  float den = fmaxf(1.0f + 2.0f * xy + x2 * y2, MINNORM);
  float h0 = (ca * v0 + cb * hb0) / den;
  float h1 = (ca * v1 + cb * hb1) / den;
  float hn = fmaxf(sqrtf(wave_sum(h0 * h0 + h1 * h1)), MINNORM);
  if (hn > MAXN) { float ps = MAXN / hn; h0 *= ps; h1 *= ps; hn = MAXN; }
  float ls = atanhf(fminf(hn, CLIPV)) / hn;   // logmap0 scale
  *reinterpret_cast<float2*>(&G[(size_t)row * 128 + lane * 2]) =
      make_float2(ls * h0, ls * h1);
}

// --- edge scatter: agg[row[e]] += ht[col[e]] (128 floats, fp32 atomics) -----
__global__ void scatter_kernel(const float* __restrict__ ht,
                               const int* __restrict__ erow,
                               const int* __restrict__ ecol,
                               float* __restrict__ agg, int E) {
  int tid = blockIdx.x * 256 + threadIdx.x;
  int e = tid >> 5;          // 32 threads per edge
  int q = tid & 31;          // each thread handles 4 consecutive floats
  if (e >= E) return;
  int r = erow[e], cn = ecol[e];
  float4 v = *reinterpret_cast<const float4*>(&ht[(size_t)cn * 128 + q * 4]);
  float* dst = &agg[(size_t)r * 128 + q * 4];
  atomicAdd(dst + 0, v.x);
  atomicAdd(dst + 1, v.y);
  atomicAdd(dst + 2, v.z);
  atomicAdd(dst + 3, v.w);
}

// --- agg -> proj(expmap0(.)) -> tanh(logmap0(.)) -> proj(expmap0(.)) --------
__global__ void agg_act_kernel(float* __restrict__ A, int M) {
  int row = blockIdx.x * 4 + (threadIdx.x >> 6);
  int lane = threadIdx.x & 63;
  if (row >= M) return;
  float2 a = *reinterpret_cast<const float2*>(&A[(size_t)row * 128 + lane * 2]);
  float an = fmaxf(sqrtf(wave_sum(a.x * a.x + a.y * a.y)), MINNORM);
  float t = tanhf(an);
  float s = t / an;
  float hn = t;
  if (hn > MAXN) { s *= MAXN / hn; hn = MAXN; }
  float ls = atanhf(fminf(hn, CLIPV)) / hn;
  float at0 = tanhf(ls * s * a.x);
  float at1 = tanhf(ls * s * a.y);
  float an2 = fmaxf(sqrtf(wave_sum(at0 * at0 + at1 * at1)), MINNORM);
  float t2 = tanhf(an2);
  float s2 = t2 / an2;
  if (t2 > MAXN) s2 *= MAXN / t2;
  *reinterpret_cast<float2*>(&A[(size_t)row * 128 + lane * 2]) =
      make_float2(s2 * at0, s2 * at1);
}

// --- final per-node logmap0(proj(h)) + segment scatter ----------------------
__global__ void pool_scatter_kernel(const float* __restrict__ H,
                                    const int* __restrict__ seg,
                                    float* __restrict__ ssum,
                                    float* __restrict__ cnt, int M) {
  int row = blockIdx.x * 4 + (threadIdx.x >> 6);
  int lane = threadIdx.x & 63;
  if (row >= M) return;
  float2 h = *reinterpret_cast<const float2*>(&H[(size_t)row * 128 + lane * 2]);
  float pn = fmaxf(sqrtf(wave_sum(h.x * h.x + h.y * h.y)), MINNORM);
  float ps = 1.0f, n = pn;
  if (n > MAXN) { ps = MAXN / n; n = MAXN; }
  float ls = atanhf(fminf(n, CLIPV)) / n * ps;
  int sg = seg[row];
  atomicAdd(&ssum[(size_t)sg * 128 + lane * 2 + 0], ls * h.x);
  atomicAdd(&ssum[(size_t)sg * 128 + lane * 2 + 1], ls * h.y);
  if (lane == 0) atomicAdd(&cnt[sg], 1.0f);
}

// --- mean + proj(expmap0(.)) -> out -----------------------------------------
__global__ void final_kernel(const float* __restrict__ ssum,
                             const float* __restrict__ cnt,
                             float* __restrict__ out, int S) {
  int row = blockIdx.x * 4 + (threadIdx.x >> 6);
  int lane = threadIdx.x & 63;
  if (row >= S) return;
  float c = fmaxf(cnt[row], 1.0f);
  float m0 = ssum[(size_t)row * 128 + lane * 2 + 0] / c;
  float m1 = ssum[(size_t)row * 128 + lane * 2 + 1] / c;
  float un = fmaxf(sqrtf(wave_sum(m0 * m0 + m1 * m1)), MINNORM);
  float t = tanhf(un);
  float s = t / un;
  if (t > MAXN) s *= MAXN / t;
  out[(size_t)row * 128 + lane * 2 + 0] = s * m0;
  out[(size_t)row * 128 + lane * 2 + 1] = s * m1;
}

extern "C" void kernel_launch(void* const* d_in, const int* in_sizes, int n_in,
                              void* d_out, int out_size, void* d_ws, size_t ws_size,
                              hipStream_t stream) {
  const float* x  = (const float*)d_in[0];
  const int* erow = (const int*)d_in[1];
  const int* ecol = (const int*)d_in[2];
  const int* seg  = (const int*)d_in[3];
  const float* W1 = (const float*)d_in[4];
  const float* b1 = (const float*)d_in[5];
  const float* W2 = (const float*)d_in[6];
  const float* b2 = (const float*)d_in[7];
  float* out = (float*)d_out;

  const int N = 100000, E = 1600000, S = 1600;

  float* W = (float*)d_ws;
  float* fbuf  = W;                  // N
  float* xnbuf = W + 100000;         // N
  float* hb1   = W + 200000;         // 128
  float* hb2   = W + 200128;         // 128
  float* y21   = W + 200256;         // 1
  float* y22   = W + 200260;         // 1
  float* B     = W + 200320;         // N*128  (GEMM out / ht)
  float* Cb    = B + 12800000;       // N*128  (agg / h)
  float* ssum  = Cb + 12800000;      // 1600*128
  float* cnt   = ssum + 204800;      // 1600

  dim3 blk(256);
  int rowBlocks = (N + 3) / 4;       // wave-per-row kernels
  int gemmBlocks = (N + 127) / 128;
  int scatBlocks = (E * 32) / 256;   // 200000

  row_scale_kernel<<<rowBlocks, blk, 0, stream>>>(x, fbuf, xnbuf, N);
  bias_kernel<<<1, 64, 0, stream>>>(b1, hb1, y21);
  bias_kernel<<<1, 64, 0, stream>>>(b2, hb2, y22);

  // ---- layer 1 ----
  gemm_xwT<<<gemmBlocks, blk, 0, stream>>>(x, W1, B, N, 256);
  post_gemm_kernel<<<rowBlocks, blk, 0, stream>>>(B, fbuf, xnbuf, nullptr, hb1, y21, N);
  hipMemsetAsync(Cb, 0, (size_t)N * 128 * sizeof(float), stream);
  scatter_kernel<<<scatBlocks, blk, 0, stream>>>(B, erow, ecol, Cb, E);
  agg_act_kernel<<<rowBlocks, blk, 0, stream>>>(Cb, N);

  // ---- layer 2 ----
  gemm_xwT<<<gemmBlocks, blk, 0, stream>>>(Cb, W2, B, N, 128);
  post_gemm_kernel<<<rowBlocks, blk, 0, stream>>>(B, nullptr, nullptr, Cb, hb2, y22, N);
  hipMemsetAsync(Cb, 0, (size_t)N * 128 * sizeof(float), stream);
  scatter_kernel<<<scatBlocks, blk, 0, stream>>>(B, erow, ecol, Cb, E);
  agg_act_kernel<<<rowBlocks, blk, 0, stream>>>(Cb, N);

  // ---- pooling ----
  hipMemsetAsync(ssum, 0, (size_t)(204800 + 1600) * sizeof(float), stream);
  pool_scatter_kernel<<<rowBlocks, blk, 0, stream>>>(Cb, seg, ssum, cnt, N);
  final_kernel<<<(S + 3) / 4, blk, 0, stream>>>(ssum, cnt, out, S);
}

// Round 2
// 986.280 us; speedup vs baseline: 6.1636x; 6.1636x over previous
//
#include <hip/hip_runtime.h>

// ---------------------------------------------------------------------------
// HypComEnc: 2-layer hyperbolic GCN encoder + segment mean pool (c = 1)
// N=100000 nodes, D0=256, D=128, E=1600000 edges, S=1600 segments
// Round 2: replace atomic edge-scatter (88% of time) with CSR build + gather.
// ---------------------------------------------------------------------------

#define MAXN 0.996f          // 1 - PROJ_EPS
#define CLIPV 0.9999999f     // 1 - 1e-7 (artanh clip)
#define MINNORM 1e-15f

__device__ __forceinline__ float wave_sum(float v) {
#pragma unroll
  for (int o = 32; o > 0; o >>= 1) v += __shfl_xor(v, o);
  return v;
}

// --- per-row scale of proj(expmap0(x)) for the 256-wide input ---------------
__global__ void row_scale_kernel(const float* __restrict__ X,
                                 float* __restrict__ fbuf,
                                 float* __restrict__ xnbuf, int M) {
  int row = blockIdx.x * 4 + (threadIdx.x >> 6);
  int lane = threadIdx.x & 63;
  if (row >= M) return;
  float4 v = *reinterpret_cast<const float4*>(&X[(size_t)row * 256 + lane * 4]);
  float ssq = wave_sum(v.x * v.x + v.y * v.y + v.z * v.z + v.w * v.w);
  float un = fmaxf(sqrtf(ssq), MINNORM);
  float t = tanhf(un);
  float f, xn;
  if (t > MAXN) { f = MAXN / un; xn = MAXN; }
  else          { f = t / un;    xn = t; }
  if (lane == 0) { fbuf[row] = f; xnbuf[row] = xn; }
}

// --- hb = proj(expmap0(b)), y2 = ||hb||^2 ; 1 block x 64 threads ------------
__global__ void bias_kernel(const float* __restrict__ b,
                            float* __restrict__ hb, float* __restrict__ y2out) {
  int lane = threadIdx.x;
  float b0 = b[lane], b1 = b[lane + 64];
  float ssq = wave_sum(b0 * b0 + b1 * b1);
  float un = fmaxf(sqrtf(ssq), MINNORM);
  float t = tanhf(un);
  float s = t / un;
  float n = t;
  if (n > MAXN) { s *= MAXN / n; n = MAXN; }
  hb[lane] = s * b0;
  hb[lane + 64] = s * b1;
  if (lane == 0) y2out[0] = n * n;
}

// --- CSR build: histogram -> exclusive scan -> placement --------------------
__global__ void hist_kernel(const int* __restrict__ erow, int* __restrict__ cnt,
                            int E) {
  int e = blockIdx.x * 256 + threadIdx.x;
  if (e < E) atomicAdd(&cnt[erow[e]], 1);
}

// scan over n elements; each block handles 1024 (256 thr x 4). If bsum!=null,
// write per-block totals. Safe for in-place single-block use (loads precede
// all writes via the barriers).
__global__ __launch_bounds__(256) void scan_kernel(const int* __restrict__ in,
                                                   int* __restrict__ out,
                                                   int* __restrict__ bsum, int n) {
  __shared__ int sh[256];
  int t = threadIdx.x;
  int base = blockIdx.x * 1024 + t * 4;
  int v0 = 0, v1 = 0, v2 = 0, v3 = 0;
  if (base + 0 < n) v0 = in[base + 0];
  if (base + 1 < n) v1 = in[base + 1];
  if (base + 2 < n) v2 = in[base + 2];
  if (base + 3 < n) v3 = in[base + 3];
  int s = v0 + v1 + v2 + v3;
  sh[t] = s;
  __syncthreads();
  int run = s;
  for (int o = 1; o < 256; o <<= 1) {
    int add = (t >= o) ? sh[t - o] : 0;
    __syncthreads();
    run += add;
    sh[t] = run;
    __syncthreads();
  }
  int excl = run - s;
  if (base + 0 < n) out[base + 0] = excl;
  if (base + 1 < n) out[base + 1] = excl + v0;
  if (base + 2 < n) out[base + 2] = excl + v0 + v1;
  if (base + 3 < n) out[base + 3] = excl + v0 + v1 + v2;
  if (t == 255 && bsum) bsum[blockIdx.x] = run;
}

__global__ void scan_add_kernel(int* __restrict__ pre, const int* __restrict__ boff,
                                int n, int total) {
  int i = blockIdx.x * 256 + threadIdx.x;
  if (i < n) pre[i] += boff[blockIdx.x >> 2];
  if (i == 0) pre[n] = total;
}

__global__ void fill_kernel(const int* __restrict__ erow, const int* __restrict__ ecol,
                            const int* __restrict__ rowptr, int* __restrict__ fill,
                            int* __restrict__ colidx, int E) {
  int e = blockIdx.x * 256 + threadIdx.x;
  if (e >= E) return;
  int r = erow[e];
  int pos = rowptr[r] + atomicAdd(&fill[r], 1);
  colidx[pos] = ecol[e];
}

// --- GEMM: Out[m][n] = sum_k X[m][k] * W[n][k], N fixed = 128 ---------------
__global__ __launch_bounds__(256) void gemm_xwT(const float* __restrict__ X,
                                                const float* __restrict__ W,
                                                float* __restrict__ Out,
                                                int M, int K) {
  __shared__ float Xs[16][132];
  __shared__ float Ws[16][132];
  int m0 = blockIdx.x * 128;
  int tid = threadIdx.x;
  int tx = tid & 15;
  int ty = tid >> 4;
  float acc[8][8];
#pragma unroll
  for (int i = 0; i < 8; i++)
#pragma unroll
    for (int j = 0; j < 8; j++) acc[i][j] = 0.f;

  for (int k0 = 0; k0 < K; k0 += 16) {
#pragma unroll
    for (int half = 0; half < 2; half++) {
      int r = (tid >> 2) + half * 64;
      int kk = (tid & 3) * 4;
      int gm = m0 + r;
      float4 v = make_float4(0.f, 0.f, 0.f, 0.f);
      if (gm < M) v = *reinterpret_cast<const float4*>(&X[(size_t)gm * K + k0 + kk]);
      Xs[kk + 0][r] = v.x; Xs[kk + 1][r] = v.y;
      Xs[kk + 2][r] = v.z; Xs[kk + 3][r] = v.w;
      int n = (tid >> 2) + half * 64;
      float4 w = *reinterpret_cast<const float4*>(&W[(size_t)n * K + k0 + kk]);
      Ws[kk + 0][n] = w.x; Ws[kk + 1][n] = w.y;
      Ws[kk + 2][n] = w.z; Ws[kk + 3][n] = w.w;
    }
    __syncthreads();
#pragma unroll
    for (int k = 0; k < 16; k++) {
      float4 a0 = *reinterpret_cast<const float4*>(&Xs[k][ty * 8]);
      float4 a1 = *reinterpret_cast<const float4*>(&Xs[k][ty * 8 + 4]);
      float4 b0 = *reinterpret_cast<const float4*>(&Ws[k][tx * 8]);
      float4 b1 = *reinterpret_cast<const float4*>(&Ws[k][tx * 8 + 4]);
      float a[8] = {a0.x, a0.y, a0.z, a0.w, a1.x, a1.y, a1.z, a1.w};
      float b[8] = {b0.x, b0.y, b0.z, b0.w, b1.x, b1.y, b1.z, b1.w};
#pragma unroll
      for (int i = 0; i < 8; i++)
#pragma unroll
        for (int j = 0; j < 8; j++) acc[i][j] = fmaf(a[i], b[j], acc[i][j]);
    }
    __syncthreads();
  }
#pragma unroll
  for (int i = 0; i < 8; i++) {
    int gm = m0 + ty * 8 + i;
    if (gm >= M) continue;
    float4 v0 = make_float4(acc[i][0], acc[i][1], acc[i][2], acc[i][3]);
    float4 v1 = make_float4(acc[i][4], acc[i][5], acc[i][6], acc[i][7]);
    *reinterpret_cast<float4*>(&Out[(size_t)gm * 128 + tx * 8]) = v0;
    *reinterpret_cast<float4*>(&Out[(size_t)gm * 128 + tx * 8 + 4]) = v1;
  }
}

// --- post-GEMM: mobius_matvec tail + proj + mobius_add(bias) + proj + logmap0
__global__ void post_gemm_kernel(float* __restrict__ G,
                                 const float* __restrict__ fbuf,
                                 const float* __restrict__ xnbuf,
                                 const float* __restrict__ Xh,
                                 const float* __restrict__ hb,
                                 const float* __restrict__ y2buf, int M) {
  int row = blockIdx.x * 4 + (threadIdx.x >> 6);
  int lane = threadIdx.x & 63;
  if (row >= M) return;
  float f, xn;
  if (fbuf) {
    f = fbuf[row]; xn = xnbuf[row];
  } else {
    f = 1.0f;
    float2 xr = *reinterpret_cast<const float2*>(&Xh[(size_t)row * 128 + lane * 2]);
    xn = fmaxf(sqrtf(wave_sum(xr.x * xr.x + xr.y * xr.y)), MINNORM);
  }
  float2 g = *reinterpret_cast<const float2*>(&G[(size_t)row * 128 + lane * 2]);
  float mx0 = f * g.x, mx1 = f * g.y;
  float mxn = fmaxf(sqrtf(wave_sum(mx0 * mx0 + mx1 * mx1)), MINNORM);
  float art = atanhf(fminf(xn, CLIPV));
  float t = tanhf(mxn / xn * art);
  float s = t / mxn;
  float rn = t;
  if (rn > MAXN) { s *= MAXN / rn; rn = MAXN; }
  float v0 = s * mx0, v1 = s * mx1;
  float x2 = rn * rn;
  float hb0 = hb[lane * 2], hb1 = hb[lane * 2 + 1];
  float y2 = y2buf[0];
  float xy = wave_sum(v0 * hb0 + v1 * hb1);
  float ca = 1.0f + 2.0f * xy + y2;
  float cb = 1.0f - x2;
  float den = fmaxf(1.0f + 2.0f * xy + x2 * y2, MINNORM);
  float h0 = (ca * v0 + cb * hb0) / den;
  float h1 = (ca * v1 + cb * hb1) / den;
  float hn = fmaxf(sqrtf(wave_sum(h0 * h0 + h1 * h1)), MINNORM);
  if (hn > MAXN) { float ps = MAXN / hn; h0 *= ps; h1 *= ps; hn = MAXN; }
  float ls = atanhf(fminf(hn, CLIPV)) / hn;
  *reinterpret_cast<float2*>(&G[(size_t)row * 128 + lane * 2]) =
      make_float2(ls * h0, ls * h1);
}

// --- CSR gather aggregation + fused activation chain ------------------------
// out[row] = proj(expmap0(tanh(logmap0(proj(expmap0( sum_{c in row} ht[c] ))))))
__global__ void agg_gather_act_kernel(const float* __restrict__ ht,
                                      const int* __restrict__ rowptr,
                                      const int* __restrict__ colidx,
                                      float* __restrict__ out, int M) {
  int row = blockIdx.x * 4 + (threadIdx.x >> 6);
  int lane = threadIdx.x & 63;
  if (row >= M) return;
  int p = rowptr[row], pe = rowptr[row + 1];
  float a0 = 0.f, a1 = 0.f, b0 = 0.f, b1 = 0.f;
  for (; p + 2 <= pe; p += 2) {
    int c0 = colidx[p], c1 = colidx[p + 1];
    float2 u = *reinterpret_cast<const float2*>(&ht[(size_t)c0 * 128 + lane * 2]);
    float2 w = *reinterpret_cast<const float2*>(&ht[(size_t)c1 * 128 + lane * 2]);
    a0 += u.x; a1 += u.y; b0 += w.x; b1 += w.y;
  }
  if (p < pe) {
    int c0 = colidx[p];
    float2 u = *reinterpret_cast<const float2*>(&ht[(size_t)c0 * 128 + lane * 2]);
    a0 += u.x; a1 += u.y;
  }
  a0 += b0; a1 += b1;
  // act: proj(expmap0(a)) -> tanh(logmap0(.)) -> proj(expmap0(.))
  float an = fmaxf(sqrtf(wave_sum(a0 * a0 + a1 * a1)), MINNORM);
  float t = tanhf(an);
  float s = t / an;
  float hn = t;
  if (hn > MAXN) { s *= MAXN / hn; hn = MAXN; }
  float ls = atanhf(fminf(hn, CLIPV)) / hn;
  float at0 = tanhf(ls * s * a0);
  float at1 = tanhf(ls * s * a1);
  float an2 = fmaxf(sqrtf(wave_sum(at0 * at0 + at1 * at1)), MINNORM);
  float t2 = tanhf(an2);
  float s2 = t2 / an2;
  if (t2 > MAXN) s2 *= MAXN / t2;
  *reinterpret_cast<float2*>(&out[(size_t)row * 128 + lane * 2]) =
      make_float2(s2 * at0, s2 * at1);
}

// --- final per-node logmap0(proj(h)) + segment scatter ----------------------
__global__ void pool_scatter_kernel(const float* __restrict__ H,
                                    const int* __restrict__ seg,
                                    float* __restrict__ ssum,
                                    float* __restrict__ cnt, int M) {
  int row = blockIdx.x * 4 + (threadIdx.x >> 6);
  int lane = threadIdx.x & 63;
  if (row >= M) return;
  float2 h = *reinterpret_cast<const float2*>(&H[(size_t)row * 128 + lane * 2]);
  float pn = fmaxf(sqrtf(wave_sum(h.x * h.x + h.y * h.y)), MINNORM);
  float ps = 1.0f, n = pn;
  if (n > MAXN) { ps = MAXN / n; n = MAXN; }
  float ls = atanhf(fminf(n, CLIPV)) / n * ps;
  int sg = seg[row];
  atomicAdd(&ssum[(size_t)sg * 128 + lane * 2 + 0], ls * h.x);
  atomicAdd(&ssum[(size_t)sg * 128 + lane * 2 + 1], ls * h.y);
  if (lane == 0) atomicAdd(&cnt[sg], 1.0f);
}

// --- mean + proj(expmap0(.)) -> out -----------------------------------------
__global__ void final_kernel(const float* __restrict__ ssum,
                             const float* __restrict__ cnt,
                             float* __restrict__ out, int S) {
  int row = blockIdx.x * 4 + (threadIdx.x >> 6);
  int lane = threadIdx.x & 63;
  if (row >= S) return;
  float c = fmaxf(cnt[row], 1.0f);
  float m0 = ssum[(size_t)row * 128 + lane * 2 + 0] / c;
  float m1 = ssum[(size_t)row * 128 + lane * 2 + 1] / c;
  float un = fmaxf(sqrtf(wave_sum(m0 * m0 + m1 * m1)), MINNORM);
  float t = tanhf(un);
  float s = t / un;
  if (t > MAXN) s *= MAXN / t;
  out[(size_t)row * 128 + lane * 2 + 0] = s * m0;
  out[(size_t)row * 128 + lane * 2 + 1] = s * m1;
}

extern "C" void kernel_launch(void* const* d_in, const int* in_sizes, int n_in,
                              void* d_out, int out_size, void* d_ws, size_t ws_size,
                              hipStream_t stream) {
  const float* x  = (const float*)d_in[0];
  const int* erow = (const int*)d_in[1];
  const int* ecol = (const int*)d_in[2];
  const int* seg  = (const int*)d_in[3];
  const float* W1 = (const float*)d_in[4];
  const float* b1 = (const float*)d_in[5];
  const float* W2 = (const float*)d_in[6];
  const float* b2 = (const float*)d_in[7];
  float* out = (float*)d_out;

  const int N = 100000, E = 1600000, S = 1600;

  float* W = (float*)d_ws;
  float* fbuf  = W;                  // N
  float* xnbuf = W + 100000;         // N
  float* hb1   = W + 200000;         // 128
  float* hb2   = W + 200128;         // 128
  float* y21   = W + 200256;         // 1
  float* y22   = W + 200260;         // 1
  float* B     = W + 200320;         // N*128  (GEMM out / ht)
  float* Cb    = B + 12800000;       // N*128  (agg / h)
  float* ssum  = Cb + 12800000;      // 1600*128
  float* cnt   = ssum + 204800;      // 1600
  int* rowptr  = (int*)(cnt + 1600); // N+1
  int* hcnt    = rowptr + 100001;    // N
  int* fill    = hcnt + 100000;      // N   (contiguous with hcnt)
  int* bsum    = fill + 100000;      // 256
  int* colidx  = bsum + 256;         // E

  dim3 blk(256);
  int rowBlocks  = (N + 3) / 4;
  int gemmBlocks = (N + 127) / 128;
  int edgeBlocks = (E + 255) / 256;
  int scanBlocks = (N + 1023) / 1024;   // 98

  // ---- CSR build (edges identical both layers; rebuilt every call) ----
  hipMemsetAsync(hcnt, 0, (size_t)200000 * sizeof(int), stream);  // hcnt + fill
  hist_kernel<<<edgeBlocks, blk, 0, stream>>>(erow, hcnt, E);
  scan_kernel<<<scanBlocks, blk, 0, stream>>>(hcnt, rowptr, bsum, N);
  scan_kernel<<<1, blk, 0, stream>>>(bsum, bsum, nullptr, scanBlocks);
  scan_add_kernel<<<(N + 255) / 256, blk, 0, stream>>>(rowptr, bsum, N, E);
  fill_kernel<<<edgeBlocks, blk, 0, stream>>>(erow, ecol, rowptr, fill, colidx, E);

  row_scale_kernel<<<rowBlocks, blk, 0, stream>>>(x, fbuf, xnbuf, N);
  bias_kernel<<<1, 64, 0, stream>>>(b1, hb1, y21);
  bias_kernel<<<1, 64, 0, stream>>>(b2, hb2, y22);

  // ---- layer 1 ----
  gemm_xwT<<<gemmBlocks, blk, 0, stream>>>(x, W1, B, N, 256);
  post_gemm_kernel<<<rowBlocks, blk, 0, stream>>>(B, fbuf, xnbuf, nullptr, hb1, y21, N);
  agg_gather_act_kernel<<<rowBlocks, blk, 0, stream>>>(B, rowptr, colidx, Cb, N);

  // ---- layer 2 ----
  gemm_xwT<<<gemmBlocks, blk, 0, stream>>>(Cb, W2, B, N, 128);
  post_gemm_kernel<<<rowBlocks, blk, 0, stream>>>(B, nullptr, nullptr, Cb, hb2, y22, N);
  agg_gather_act_kernel<<<rowBlocks, blk, 0, stream>>>(B, rowptr, colidx, Cb, N);

  // ---- pooling ----
  hipMemsetAsync(ssum, 0, (size_t)(204800 + 1600) * sizeof(float), stream);
  pool_scatter_kernel<<<rowBlocks, blk, 0, stream>>>(Cb, seg, ssum, cnt, N);
  final_kernel<<<(S + 3) / 4, blk, 0, stream>>>(ssum, cnt, out, S);
}

// Round 3
// 840.120 us; speedup vs baseline: 7.2359x; 1.1740x over previous
//
#include <hip/hip_runtime.h>

// ---------------------------------------------------------------------------
// HypComEnc: 2-layer hyperbolic GCN encoder + segment mean pool (c = 1)
// N=100000 nodes, D0=256, D=128, E=1600000 edges, S=1600 segments
// Round 3: bf16 MFMA GEMM + bf16 node tables (ht/Cb) to cut gather traffic.
// ---------------------------------------------------------------------------

#define MAXN 0.996f          // 1 - PROJ_EPS
#define CLIPV 0.9999999f     // 1 - 1e-7 (artanh clip)
#define MINNORM 1e-15f

typedef __attribute__((ext_vector_type(8))) short  short8;
typedef __attribute__((ext_vector_type(4))) float  f32x4;
typedef __attribute__((ext_vector_type(4))) unsigned short us4;

__device__ __forceinline__ float wave_sum(float v) {
#pragma unroll
  for (int o = 32; o > 0; o >>= 1) v += __shfl_xor(v, o);
  return v;
}

__device__ __forceinline__ unsigned short f2bf(float f) {
  unsigned int u = __float_as_uint(f);
  u = (u + 0x7FFFu + ((u >> 16) & 1u)) >> 16;   // RNE
  return (unsigned short)u;
}
__device__ __forceinline__ float bf_lo(unsigned int u) {
  return __uint_as_float(u << 16);
}
__device__ __forceinline__ float bf_hi(unsigned int u) {
  return __uint_as_float(u & 0xFFFF0000u);
}

// --- per-row scale of proj(expmap0(x)) for the 256-wide input ---------------
__global__ void row_scale_kernel(const float* __restrict__ X,
                                 float* __restrict__ fbuf,
                                 float* __restrict__ xnbuf, int M) {
  int row = blockIdx.x * 4 + (threadIdx.x >> 6);
  int lane = threadIdx.x & 63;
  if (row >= M) return;
  float4 v = *reinterpret_cast<const float4*>(&X[(size_t)row * 256 + lane * 4]);
  float ssq = wave_sum(v.x * v.x + v.y * v.y + v.z * v.z + v.w * v.w);
  float un = fmaxf(sqrtf(ssq), MINNORM);
  float t = tanhf(un);
  float f, xn;
  if (t > MAXN) { f = MAXN / un; xn = MAXN; }
  else          { f = t / un;    xn = t; }
  if (lane == 0) { fbuf[row] = f; xnbuf[row] = xn; }
}

// --- hb = proj(expmap0(b)), y2 = ||hb||^2 ; 1 block x 64 threads ------------
__global__ void bias_kernel(const float* __restrict__ b,
                            float* __restrict__ hb, float* __restrict__ y2out) {
  int lane = threadIdx.x;
  float b0 = b[lane], b1 = b[lane + 64];
  float ssq = wave_sum(b0 * b0 + b1 * b1);
  float un = fmaxf(sqrtf(ssq), MINNORM);
  float t = tanhf(un);
  float s = t / un;
  float n = t;
  if (n > MAXN) { s *= MAXN / n; n = MAXN; }
  hb[lane] = s * b0;
  hb[lane + 64] = s * b1;
  if (lane == 0) y2out[0] = n * n;
}

// --- CSR build: histogram -> exclusive scan -> placement --------------------
__global__ void hist_kernel(const int* __restrict__ erow, int* __restrict__ cnt,
                            int E) {
  int e = blockIdx.x * 256 + threadIdx.x;
  if (e < E) atomicAdd(&cnt[erow[e]], 1);
}

__global__ __launch_bounds__(256) void scan_kernel(const int* __restrict__ in,
                                                   int* __restrict__ out,
                                                   int* __restrict__ bsum, int n) {
  __shared__ int sh[256];
  int t = threadIdx.x;
  int base = blockIdx.x * 1024 + t * 4;
  int v0 = 0, v1 = 0, v2 = 0, v3 = 0;
  if (base + 0 < n) v0 = in[base + 0];
  if (base + 1 < n) v1 = in[base + 1];
  if (base + 2 < n) v2 = in[base + 2];
  if (base + 3 < n) v3 = in[base + 3];
  int s = v0 + v1 + v2 + v3;
  sh[t] = s;
  __syncthreads();
  int run = s;
  for (int o = 1; o < 256; o <<= 1) {
    int add = (t >= o) ? sh[t - o] : 0;
    __syncthreads();
    run += add;
    sh[t] = run;
    __syncthreads();
  }
  int excl = run - s;
  if (base + 0 < n) out[base + 0] = excl;
  if (base + 1 < n) out[base + 1] = excl + v0;
  if (base + 2 < n) out[base + 2] = excl + v0 + v1;
  if (base + 3 < n) out[base + 3] = excl + v0 + v1 + v2;
  if (t == 255 && bsum) bsum[blockIdx.x] = run;
}

__global__ void scan_add_kernel(int* __restrict__ pre, const int* __restrict__ boff,
                                int n, int total) {
  int i = blockIdx.x * 256 + threadIdx.x;
  if (i < n) pre[i] += boff[blockIdx.x >> 2];
  if (i == 0) pre[n] = total;
}

__global__ void fill_kernel(const int* __restrict__ erow, const int* __restrict__ ecol,
                            const int* __restrict__ rowptr, int* __restrict__ fill,
                            int* __restrict__ colidx, int E) {
  int e = blockIdx.x * 256 + threadIdx.x;
  if (e >= E) return;
  int r = erow[e];
  int pos = rowptr[r] + atomicAdd(&fill[r], 1);
  colidx[pos] = ecol[e];
}

// --- MFMA GEMM: Out[m][n] = sum_k X[m][k]*W[n][k], n=128, bf16 inputs -------
// 128x128 tile, 4 waves (64x64 each, 4x4 16x16 frags), BK=32.
// LDS layout per operand: 4 k-groups of [128 rows][8 bf16]; group stride
// padded +16B. Fragment read = ds_read_b128, 16 consecutive lanes read
// 256B linear -> conflict-free.
template <bool SRC_BF16>
__global__ __launch_bounds__(256) void gemm_mfma(const void* __restrict__ Xv,
                                                 const float* __restrict__ Wt,
                                                 float* __restrict__ Out,
                                                 int M, int K) {
  constexpr int GS = 128 * 16 + 16;          // 2064 B group stride
  __shared__ alignas(16) char smem[8 * GS];  // A: groups 0..3, B: groups 4..7
  char* sA = smem;
  char* sB = smem + 4 * GS;
  int tid = threadIdx.x;
  int lane = tid & 63;
  int w = tid >> 6;
  int wr = w >> 1, wc = w & 1;
  int m0 = blockIdx.x * 128;
  f32x4 acc[4][4] = {};

  for (int k0 = 0; k0 < K; k0 += 32) {
#pragma unroll
    for (int j = 0; j < 4; j++) {
      int i = tid + 256 * j;
      int row = i >> 3;
      int koff = (i & 7) * 4;
      int gm = m0 + row;
      us4 av;
      if (SRC_BF16) {
        if (gm < M) av = *reinterpret_cast<const us4*>(
            &((const unsigned short*)Xv)[(size_t)gm * K + k0 + koff]);
        else { av[0] = 0; av[1] = 0; av[2] = 0; av[3] = 0; }
      } else {
        if (gm < M) {
          float4 v = *reinterpret_cast<const float4*>(
              &((const float*)Xv)[(size_t)gm * K + k0 + koff]);
          av[0] = f2bf(v.x); av[1] = f2bf(v.y); av[2] = f2bf(v.z); av[3] = f2bf(v.w);
        } else { av[0] = 0; av[1] = 0; av[2] = 0; av[3] = 0; }
      }
      *reinterpret_cast<us4*>(&sA[(koff >> 3) * GS + row * 16 + (koff & 7) * 2]) = av;
      float4 wv = *reinterpret_cast<const float4*>(&Wt[(size_t)row * K + k0 + koff]);
      us4 bv;
      bv[0] = f2bf(wv.x); bv[1] = f2bf(wv.y); bv[2] = f2bf(wv.z); bv[3] = f2bf(wv.w);
      *reinterpret_cast<us4*>(&sB[(koff >> 3) * GS + row * 16 + (koff & 7) * 2]) = bv;
    }
    __syncthreads();
    int g = lane >> 4, r = lane & 15;
    short8 af[4], bfr[4];
#pragma unroll
    for (int mb = 0; mb < 4; mb++)
      af[mb] = *reinterpret_cast<const short8*>(
          &sA[g * GS + (wr * 64 + mb * 16 + r) * 16]);
#pragma unroll
    for (int nb = 0; nb < 4; nb++)
      bfr[nb] = *reinterpret_cast<const short8*>(
          &sB[g * GS + (wc * 64 + nb * 16 + r) * 16]);
#pragma unroll
    for (int mb = 0; mb < 4; mb++)
#pragma unroll
      for (int nb = 0; nb < 4; nb++)
        acc[mb][nb] = __builtin_amdgcn_mfma_f32_16x16x32_bf16(
            af[mb], bfr[nb], acc[mb][nb], 0, 0, 0);
    __syncthreads();
  }
  // epilogue: C/D layout col=lane&15, row=(lane>>4)*4+q  [learn_hip m89]
  int cr = lane >> 4, cc = lane & 15;
#pragma unroll
  for (int mb = 0; mb < 4; mb++)
#pragma unroll
    for (int q = 0; q < 4; q++) {
      int gm = m0 + wr * 64 + mb * 16 + cr * 4 + q;
      if (gm >= M) continue;
#pragma unroll
      for (int nb = 0; nb < 4; nb++)
        Out[(size_t)gm * 128 + wc * 64 + nb * 16 + cc] = acc[mb][nb][q];
    }
}

// --- post-GEMM: mobius_matvec tail + proj + mobius_add(bias) + proj + logmap0
// G fp32 in; HT packed bf16 out (2 per uint). Layer 2: xn from bf16 Xb row.
__global__ void post_gemm_kernel(const float* __restrict__ G,
                                 const float* __restrict__ fbuf,
                                 const float* __restrict__ xnbuf,
                                 const unsigned int* __restrict__ Xb,
                                 const float* __restrict__ hb,
                                 const float* __restrict__ y2buf,
                                 unsigned int* __restrict__ HT, int M) {
  int row = blockIdx.x * 4 + (threadIdx.x >> 6);
  int lane = threadIdx.x & 63;
  if (row >= M) return;
  float f, xn;
  if (fbuf) {
    f = fbuf[row]; xn = xnbuf[row];
  } else {
    f = 1.0f;
    unsigned int u = Xb[(size_t)row * 64 + lane];
    float x0 = bf_lo(u), x1 = bf_hi(u);
    xn = fmaxf(sqrtf(wave_sum(x0 * x0 + x1 * x1)), MINNORM);
  }
  float2 g = *reinterpret_cast<const float2*>(&G[(size_t)row * 128 + lane * 2]);
  float mx0 = f * g.x, mx1 = f * g.y;
  float mxn = fmaxf(sqrtf(wave_sum(mx0 * mx0 + mx1 * mx1)), MINNORM);
  float art = atanhf(fminf(xn, CLIPV));
  float t = tanhf(mxn / xn * art);
  float s = t / mxn;
  float rn = t;
  if (rn > MAXN) { s *= MAXN / rn; rn = MAXN; }
  float v0 = s * mx0, v1 = s * mx1;
  float x2 = rn * rn;
  float hb0 = hb[lane * 2], hb1 = hb[lane * 2 + 1];
  float y2 = y2buf[0];
  float xy = wave_sum(v0 * hb0 + v1 * hb1);
  float ca = 1.0f + 2.0f * xy + y2;
  float cb = 1.0f - x2;
  float den = fmaxf(1.0f + 2.0f * xy + x2 * y2, MINNORM);
  float h0 = (ca * v0 + cb * hb0) / den;
  float h1 = (ca * v1 + cb * hb1) / den;
  float hn = fmaxf(sqrtf(wave_sum(h0 * h0 + h1 * h1)), MINNORM);
  if (hn > MAXN) { float ps = MAXN / hn; h0 *= ps; h1 *= ps; hn = MAXN; }
  float ls = atanhf(fminf(hn, CLIPV)) / hn;
  HT[(size_t)row * 64 + lane] =
      (unsigned int)f2bf(ls * h0) | ((unsigned int)f2bf(ls * h1) << 16);
}

// --- CSR gather aggregation + fused activation chain (bf16 table) -----------
__global__ void agg_gather_act_kernel(const unsigned int* __restrict__ ht,
                                      const int* __restrict__ rowptr,
                                      const int* __restrict__ colidx,
                                      unsigned int* __restrict__ out, int M) {
  int row = blockIdx.x * 4 + (threadIdx.x >> 6);
  int lane = threadIdx.x & 63;
  if (row >= M) return;
  int p = rowptr[row], pe = rowptr[row + 1];
  float a0 = 0.f, a1 = 0.f, b0 = 0.f, b1 = 0.f;
  for (; p + 2 <= pe; p += 2) {
    int c0 = colidx[p], c1 = colidx[p + 1];
    unsigned int u = ht[(size_t)c0 * 64 + lane];
    unsigned int v = ht[(size_t)c1 * 64 + lane];
    a0 += bf_lo(u); a1 += bf_hi(u);
    b0 += bf_lo(v); b1 += bf_hi(v);
  }
  if (p < pe) {
    unsigned int u = ht[(size_t)colidx[p] * 64 + lane];
    a0 += bf_lo(u); a1 += bf_hi(u);
  }
  a0 += b0; a1 += b1;
  float an = fmaxf(sqrtf(wave_sum(a0 * a0 + a1 * a1)), MINNORM);
  float t = tanhf(an);
  float s = t / an;
  float hn = t;
  if (hn > MAXN) { s *= MAXN / hn; hn = MAXN; }
  float ls = atanhf(fminf(hn, CLIPV)) / hn;
  float at0 = tanhf(ls * s * a0);
  float at1 = tanhf(ls * s * a1);
  float an2 = fmaxf(sqrtf(wave_sum(at0 * at0 + at1 * at1)), MINNORM);
  float t2 = tanhf(an2);
  float s2 = t2 / an2;
  if (t2 > MAXN) s2 *= MAXN / t2;
  out[(size_t)row * 64 + lane] =
      (unsigned int)f2bf(s2 * at0) | ((unsigned int)f2bf(s2 * at1) << 16);
}

// --- final per-node logmap0(proj(h)) + segment scatter (bf16 in) ------------
__global__ void pool_scatter_kernel(const unsigned int* __restrict__ H,
                                    const int* __restrict__ seg,
                                    float* __restrict__ ssum,
                                    float* __restrict__ cnt, int M) {
  int row = blockIdx.x * 4 + (threadIdx.x >> 6);
  int lane = threadIdx.x & 63;
  if (row >= M) return;
  unsigned int u = H[(size_t)row * 64 + lane];
  float h0 = bf_lo(u), h1 = bf_hi(u);
  float pn = fmaxf(sqrtf(wave_sum(h0 * h0 + h1 * h1)), MINNORM);
  float ps = 1.0f, n = pn;
  if (n > MAXN) { ps = MAXN / n; n = MAXN; }
  float ls = atanhf(fminf(n, CLIPV)) / n * ps;
  int sg = seg[row];
  atomicAdd(&ssum[(size_t)sg * 128 + lane * 2 + 0], ls * h0);
  atomicAdd(&ssum[(size_t)sg * 128 + lane * 2 + 1], ls * h1);
  if (lane == 0) atomicAdd(&cnt[sg], 1.0f);
}

// --- mean + proj(expmap0(.)) -> out -----------------------------------------
__global__ void final_kernel(const float* __restrict__ ssum,
                             const float* __restrict__ cnt,
                             float* __restrict__ out, int S) {
  int row = blockIdx.x * 4 + (threadIdx.x >> 6);
  int lane = threadIdx.x & 63;
  if (row >= S) return;
  float c = fmaxf(cnt[row], 1.0f);
  float m0 = ssum[(size_t)row * 128 + lane * 2 + 0] / c;
  float m1 = ssum[(size_t)row * 128 + lane * 2 + 1] / c;
  float un = fmaxf(sqrtf(wave_sum(m0 * m0 + m1 * m1)), MINNORM);
  float t = tanhf(un);
  float s = t / un;
  if (t > MAXN) s *= MAXN / t;
  out[(size_t)row * 128 + lane * 2 + 0] = s * m0;
  out[(size_t)row * 128 + lane * 2 + 1] = s * m1;
}

extern "C" void kernel_launch(void* const* d_in, const int* in_sizes, int n_in,
                              void* d_out, int out_size, void* d_ws, size_t ws_size,
                              hipStream_t stream) {
  const float* x  = (const float*)d_in[0];
  const int* erow = (const int*)d_in[1];
  const int* ecol = (const int*)d_in[2];
  const int* seg  = (const int*)d_in[3];
  const float* W1 = (const float*)d_in[4];
  const float* b1 = (const float*)d_in[5];
  const float* W2 = (const float*)d_in[6];
  const float* b2 = (const float*)d_in[7];
  float* out = (float*)d_out;

  const int N = 100000, E = 1600000, S = 1600;

  float* W = (float*)d_ws;
  float* fbuf  = W;                     // N
  float* xnbuf = W + 100000;            // N
  float* hb1   = W + 200000;            // 128
  float* hb2   = W + 200128;            // 128
  float* y21   = W + 200256;            // 1
  float* y22   = W + 200260;            // 1
  float* G     = W + 200320;            // N*128 fp32 (GEMM out)
  unsigned int* HT = (unsigned int*)(G + 12800000);   // N*64 uints (bf16 x2)
  unsigned int* CB = HT + 6400000;      // N*64 uints (bf16 x2)
  float* ssum  = (float*)(CB + 6400000);// 1600*128
  float* cnt   = ssum + 204800;         // 1600
  int* rowptr  = (int*)(cnt + 1600);    // N+1
  int* hcnt    = rowptr + 100001;       // N
  int* fill    = hcnt + 100000;         // N (contiguous with hcnt for memset)
  int* bsum    = fill + 100000;         // 256
  int* colidx  = bsum + 256;            // E

  dim3 blk(256);
  int rowBlocks  = (N + 3) / 4;
  int gemmBlocks = (N + 127) / 128;
  int edgeBlocks = (E + 255) / 256;
  int scanBlocks = (N + 1023) / 1024;

  // ---- CSR build ----
  hipMemsetAsync(hcnt, 0, (size_t)200000 * sizeof(int), stream);
  hist_kernel<<<edgeBlocks, blk, 0, stream>>>(erow, hcnt, E);
  scan_kernel<<<scanBlocks, blk, 0, stream>>>(hcnt, rowptr, bsum, N);
  scan_kernel<<<1, blk, 0, stream>>>(bsum, bsum, nullptr, scanBlocks);
  scan_add_kernel<<<(N + 255) / 256, blk, 0, stream>>>(rowptr, bsum, N, E);
  fill_kernel<<<edgeBlocks, blk, 0, stream>>>(erow, ecol, rowptr, fill, colidx, E);

  row_scale_kernel<<<rowBlocks, blk, 0, stream>>>(x, fbuf, xnbuf, N);
  bias_kernel<<<1, 64, 0, stream>>>(b1, hb1, y21);
  bias_kernel<<<1, 64, 0, stream>>>(b2, hb2, y22);

  // ---- layer 1 ----
  gemm_mfma<false><<<gemmBlocks, blk, 0, stream>>>(x, W1, G, N, 256);
  post_gemm_kernel<<<rowBlocks, blk, 0, stream>>>(G, fbuf, xnbuf, nullptr, hb1, y21, HT, N);
  agg_gather_act_kernel<<<rowBlocks, blk, 0, stream>>>(HT, rowptr, colidx, CB, N);

  // ---- layer 2 ----
  gemm_mfma<true><<<gemmBlocks, blk, 0, stream>>>(CB, W2, G, N, 128);
  post_gemm_kernel<<<rowBlocks, blk, 0, stream>>>(G, nullptr, nullptr, CB, hb2, y22, HT, N);
  agg_gather_act_kernel<<<rowBlocks, blk, 0, stream>>>(HT, rowptr, colidx, CB, N);

  // ---- pooling ----
  hipMemsetAsync(ssum, 0, (size_t)(204800 + 1600) * sizeof(float), stream);
  pool_scatter_kernel<<<rowBlocks, blk, 0, stream>>>(CB, seg, ssum, cnt, N);
  final_kernel<<<(S + 3) / 4, blk, 0, stream>>>(ssum, cnt, out, S);
}